// Round 11
// baseline (5127.420 us; speedup 1.0000x reference)
//
#include <hip/hip_runtime.h>

// Seq2SeqLSTMForecaster on MI355X — round 11.
// R10 analysis: recurrent kernels are LDS-*instruction*-bound (conflicts
// measured low; it's issue count). Two cuts, structure unchanged from R10:
//  1) zp gate-interleaved [kq][batch][hid][4]: dot writes 4xb128 (was 16xb32),
//     act reads 4xb128 (was 16xb32). Applied to kA, kB2, both kD dots.
//  2) kD head split-k in REGISTERS: wh[32]/thread (Wo1[hid][bb*32..+32)),
//     4 batch-partials from UNIFORM h2t reads, 8KB part[] LDS reduce
//     (+1 barrier). Kills the 32 lane-spread wq reads and the 67KB wo1s.

#define B_    1024
#define T_    672
#define H_    128
#define G_    512      // 4*H
#define TGT_  96
#define NBLK_ 256

__device__ __forceinline__ float sigm(float x)   { return 1.f / (1.f + __expf(-x)); }
__device__ __forceinline__ float tanh_f(float x) { return 1.f - 2.f / (1.f + __expf(2.f * x)); }

// ---------------------------------------------------------------- prep ------
struct PrepArgs {
    const float* t_src[4];   // eWhh0, eWih1, eWhh1, dWhh0 -> [128,512]
    float*       t_dst[4];
    const float* d1x;  const float* d1h;  float* pack;   // dec L1 8-wide pack
};

__global__ void kPrep(PrepArgs a) {
    const int m = blockIdx.x;
    if (m < 4) {
        for (int i = threadIdx.x; i < G_ * H_; i += blockDim.x) {
            const int j = i >> 7, k = i & 127;
            a.t_dst[m][k * G_ + j] = a.t_src[m][i];
        }
    } else {
        // pack[(k*128 + j4)*8 + g]   = dWih1[j4+128g][k]  (g=0..3)
        // pack[(k*128 + j4)*8 + 4+g] = dWhh1[j4+128g][k]
        for (int i = threadIdx.x; i < H_ * H_; i += blockDim.x) {
            const int k = i >> 7, j4 = i & 127;
            float* p = a.pack + ((size_t)k * H_ + j4) * 8;
#pragma unroll
            for (int g = 0; g < 4; g++) {
                p[g]     = a.d1x[(j4 + 128 * g) * H_ + k];
                p[4 + g] = a.d1h[(j4 + 128 * g) * H_ + k];
            }
        }
    }
}

// --------------------------------- enc L0 (quad-gate, 4-way k, 512 thr) -----
__global__ __launch_bounds__(512, 2) void kA(
    const float* __restrict__ feat,   // [B,T]
    const float* __restrict__ whhT,   // [128,512] enc_Whh0^T
    const float* __restrict__ wih0,   // [512]
    const float* __restrict__ bias,   // [512]
    float* __restrict__ ys0T,         // [CL][128][1024] k-major
    float* __restrict__ hS, float* __restrict__ cS,
    int t0, int CL)
{
    __shared__ __align__(16) float h_sh[H_ * 4];     // [hid][bb]
    __shared__ __align__(16) float zp[4 * 2048];     // [kq][batch][hid][4]
    __shared__ __align__(16) float f_sh[84 * 4];

    const int tid = threadIdx.x;
    const int hid = tid & 127;        // gate group (dot) / act hid
    const int bb  = tid >> 7;         // k-quarter (dot) / act batch
    const int B0  = blockIdx.x * 4;

    float w[4][32];
#pragma unroll
    for (int g = 0; g < 4; g++)
#pragma unroll
        for (int k = 0; k < 32; k++)
            w[g][k] = whhT[(bb * 32 + k) * G_ + hid + 128 * g];

    const float bi = bias[hid],           bf = bias[hid + 128];
    const float bg = bias[hid + 256],     bo = bias[hid + 384];
    const float wxi = wih0[hid],          wxf = wih0[hid + 128];
    const float wxg = wih0[hid + 256],    wxo = wih0[hid + 384];

    for (int i = tid; i < CL * 4; i += 512)
        f_sh[i] = feat[(B0 + (i & 3)) * T_ + t0 + (i >> 2)];

    float c = 0.f;
    {
        float hv = 0.f;
        if (t0 != 0) { c = cS[(B0 + bb) * H_ + hid]; hv = hS[(B0 + bb) * H_ + hid]; }
        h_sh[hid * 4 + bb] = hv;
    }
    __syncthreads();

    const float* hb = h_sh + bb * 128;
    for (int dt = 0; dt < CL; dt++) {
        if (dt > 0)
            ys0T[((size_t)(dt - 1) * H_ + (tid >> 2)) * B_ + B0 + (tid & 3)] = h_sh[tid];

        float a[4][4] = {};
#pragma unroll
        for (int k = 0; k < 32; k++) {
            const float4 h4 = *(const float4*)&hb[k * 4];   // uniform broadcast
#pragma unroll
            for (int g = 0; g < 4; g++) {
                a[g][0] = __fmaf_rn(h4.x, w[g][k], a[g][0]);
                a[g][1] = __fmaf_rn(h4.y, w[g][k], a[g][1]);
                a[g][2] = __fmaf_rn(h4.z, w[g][k], a[g][2]);
                a[g][3] = __fmaf_rn(h4.w, w[g][k], a[g][3]);
            }
        }
#pragma unroll
        for (int b = 0; b < 4; b++) {
            float4 v; v.x = a[0][b]; v.y = a[1][b]; v.z = a[2][b]; v.w = a[3][b];
            *(float4*)&zp[bb * 2048 + b * 512 + hid * 4] = v;   // lanes stride 16B
        }
        __syncthreads();

        {
            const float x = f_sh[dt * 4 + bb];
            float zi = __fmaf_rn(wxi, x, bi);
            float zf = __fmaf_rn(wxf, x, bf);
            float zg = __fmaf_rn(wxg, x, bg);
            float zo = __fmaf_rn(wxo, x, bo);
#pragma unroll
            for (int q = 0; q < 4; q++) {
                const float4 v = *(const float4*)&zp[q * 2048 + bb * 512 + hid * 4];
                zi += v.x; zf += v.y; zg += v.z; zo += v.w;
            }
            c = sigm(zf) * c + sigm(zi) * tanh_f(zg);
            h_sh[hid * 4 + bb] = sigm(zo) * tanh_f(c);
        }
        __syncthreads();
    }
    ys0T[((size_t)(CL - 1) * H_ + (tid >> 2)) * B_ + B0 + (tid & 3)] = h_sh[tid];
    hS[(B0 + bb) * H_ + hid] = h_sh[hid * 4 + bb];
    cS[(B0 + bb) * H_ + hid] = c;
}

// ----------------------- X1 GEMM: 128x128 tile, 8x8 micro, split-B ----------
__global__ __launch_bounds__(256, 2) void kX(
    const float* __restrict__ ys0T,   // [CL][128][1024]
    const float* __restrict__ wT,     // [128][512]
    const float* __restrict__ bias,   // [512]
    float* __restrict__ X1)           // [CL][1024][512]
{
    __shared__ __align__(16) float As[64][132];
    __shared__ __align__(16) float Bs[64][132];

    const int tid = threadIdx.x;
    const int m0 = blockIdx.x * 128;
    const int n0 = blockIdx.y * 128;
    const int dt = blockIdx.z;
    const float* A = ys0T + (size_t)dt * H_ * B_;

    const int tx = tid & 15, ty = tid >> 4;
    float acc[8][8] = {};

#pragma unroll
    for (int ks = 0; ks < 2; ks++) {
        if (ks) __syncthreads();
        for (int t = tid; t < 64 * 32; t += 256) {
            const int r = t >> 5, q = t & 31;
            *(float4*)&As[r][q * 4] = *(const float4*)&A[(size_t)(ks * 64 + r) * B_ + m0 + q * 4];
        }
        for (int t = tid; t < 64 * 32; t += 256) {
            const int r = t >> 5, q = t & 31;
            *(float4*)&Bs[r][q * 4] = *(const float4*)&wT[(size_t)(ks * 64 + r) * G_ + n0 + q * 4];
        }
        __syncthreads();

#pragma unroll 4
        for (int k = 0; k < 64; k++) {
            float av[8], bv[8];
            *(float4*)&av[0] = *(const float4*)&As[k][ty * 8];
            *(float4*)&av[4] = *(const float4*)&As[k][ty * 8 + 4];
            *(float4*)&bv[0] = *(const float4*)&Bs[k][tx * 4];
            *(float4*)&bv[4] = *(const float4*)&Bs[k][64 + tx * 4];
#pragma unroll
            for (int i = 0; i < 8; i++)
#pragma unroll
                for (int j = 0; j < 8; j++)
                    acc[i][j] = __fmaf_rn(av[i], bv[j], acc[i][j]);
        }
    }

    float4 bv0 = *(const float4*)&bias[n0 + tx * 4];
    float4 bv1 = *(const float4*)&bias[n0 + 64 + tx * 4];
#pragma unroll
    for (int i = 0; i < 8; i++) {
        float4 o0, o1;
        o0.x = acc[i][0] + bv0.x; o0.y = acc[i][1] + bv0.y;
        o0.z = acc[i][2] + bv0.z; o0.w = acc[i][3] + bv0.w;
        o1.x = acc[i][4] + bv1.x; o1.y = acc[i][5] + bv1.y;
        o1.z = acc[i][6] + bv1.z; o1.w = acc[i][7] + bv1.w;
        float* orow = &X1[((size_t)dt * B_ + m0 + ty * 8 + i) * G_ + n0];
        *(float4*)&orow[tx * 4]      = o0;
        *(float4*)&orow[64 + tx * 4] = o1;
    }
}

// --------------------------------- enc L1 (quad-gate, 4-way k, 512 thr) -----
__global__ __launch_bounds__(512, 2) void kB2(
    const float* __restrict__ X1,     // [CL][B][512] x-projection (+bias)
    const float* __restrict__ whhT,   // [128,512] enc_Whh1^T
    float* __restrict__ hS, float* __restrict__ cS,
    int t0, int CL)
{
    __shared__ __align__(16) float h_sh[H_ * 4];
    __shared__ __align__(16) float zp[4 * 2048];     // [kq][batch][hid][4]

    const int tid = threadIdx.x;
    const int hid = tid & 127;
    const int bb  = tid >> 7;
    const int B0  = blockIdx.x * 4;

    float w[4][32];
#pragma unroll
    for (int g = 0; g < 4; g++)
#pragma unroll
        for (int k = 0; k < 32; k++)
            w[g][k] = whhT[(bb * 32 + k) * G_ + hid + 128 * g];

    float c = 0.f;
    {
        float hv = 0.f;
        if (t0 != 0) { c = cS[(B0 + bb) * H_ + hid]; hv = hS[(B0 + bb) * H_ + hid]; }
        h_sh[hid * 4 + bb] = hv;
    }
    __syncthreads();

    const float* hb = h_sh + bb * 128;
    for (int dt = 0; dt < CL; dt++) {
        const size_t xb = ((size_t)dt * B_ + B0 + bb) * G_ + hid;
        const float xg0 = X1[xb];
        const float xg1 = X1[xb + 128];
        const float xg2 = X1[xb + 256];
        const float xg3 = X1[xb + 384];

        float a[4][4] = {};
#pragma unroll
        for (int k = 0; k < 32; k++) {
            const float4 h4 = *(const float4*)&hb[k * 4];
#pragma unroll
            for (int g = 0; g < 4; g++) {
                a[g][0] = __fmaf_rn(h4.x, w[g][k], a[g][0]);
                a[g][1] = __fmaf_rn(h4.y, w[g][k], a[g][1]);
                a[g][2] = __fmaf_rn(h4.z, w[g][k], a[g][2]);
                a[g][3] = __fmaf_rn(h4.w, w[g][k], a[g][3]);
            }
        }
#pragma unroll
        for (int b = 0; b < 4; b++) {
            float4 v; v.x = a[0][b]; v.y = a[1][b]; v.z = a[2][b]; v.w = a[3][b];
            *(float4*)&zp[bb * 2048 + b * 512 + hid * 4] = v;
        }
        __syncthreads();

        {
            float zi = xg0, zf = xg1, zg = xg2, zo = xg3;
#pragma unroll
            for (int q = 0; q < 4; q++) {
                const float4 v = *(const float4*)&zp[q * 2048 + bb * 512 + hid * 4];
                zi += v.x; zf += v.y; zg += v.z; zo += v.w;
            }
            c = sigm(zf) * c + sigm(zi) * tanh_f(zg);
            h_sh[hid * 4 + bb] = sigm(zo) * tanh_f(c);
        }
        __syncthreads();
    }
    hS[(B0 + bb) * H_ + hid] = h_sh[hid * 4 + bb];
    cS[(B0 + bb) * H_ + hid] = c;
}

// ------------------- decoder (quad-gate dots, split-k register head) --------
__global__ __launch_bounds__(512, 2) void kD(
    const float* __restrict__ h1S, const float* __restrict__ c1S,
    const float* __restrict__ h2S, const float* __restrict__ c2S,
    const float* __restrict__ whh0T,  // [128][512] dec_Whh0^T (register-resident)
    const float* __restrict__ wih0,   // [512]
    const float* __restrict__ b0,
    const float* __restrict__ packD1, // [128][128][8]
    const float* __restrict__ b1,
    const float* __restrict__ wo1,    // [128][128] W_out1 [hid][k] -> wh regs
    const float* __restrict__ bo1,
    const float* __restrict__ wo2,
    const float* __restrict__ bo2,
    float* __restrict__ out)          // [B,TGT]
{
    __shared__ __align__(16) float h1_sh[H_ * 4];
    __shared__ __align__(16) float h2_sh[H_ * 4];
    __shared__ __align__(16) float h2t[4][H_];       // [batch][k]
    __shared__ __align__(16) float zp[4 * 2048];     // [kq][batch][hid][4]
    __shared__ __align__(16) float part[4 * 512];    // [kq][batch][hid] 8KB
    __shared__ float rp[8];

    const int tid = threadIdx.x;
    const int hid = tid & 127;        // gate group / act hid
    const int bb  = tid >> 7;         // k-quarter / act batch
    const int B0  = blockIdx.x * 4;

    float w0[4][32];
#pragma unroll
    for (int g = 0; g < 4; g++)
#pragma unroll
        for (int k = 0; k < 32; k++)
            w0[g][k] = whh0T[(bb * 32 + k) * G_ + hid + 128 * g];

    // head weights: this thread's k-range of Wo1 row hid (32 regs)
    float wh[32];
#pragma unroll
    for (int k = 0; k < 32; k++) wh[k] = wo1[hid * H_ + bb * 32 + k];

    const float b0i = b0[hid],        b0f = b0[hid + 128];
    const float b0g = b0[hid + 256],  b0o = b0[hid + 384];
    const float wxi = wih0[hid],      wxf = wih0[hid + 128];
    const float wxg = wih0[hid + 256], wxo = wih0[hid + 384];
    const float b1i = b1[hid],        b1f = b1[hid + 128];
    const float b1g = b1[hid + 256],  b1o = b1[hid + 384];

    const float wo2v = wo2[hid];
    const float bo1j = bo1[hid];
    const float bo2v = bo2[0];

    float c1 = c1S[(B0 + bb) * H_ + hid];
    float c2 = c2S[(B0 + bb) * H_ + hid];
    h1_sh[hid * 4 + bb] = h1S[(B0 + bb) * H_ + hid];
    {
        const float h2v = h2S[(B0 + bb) * H_ + hid];
        h2_sh[hid * 4 + bb] = h2v;
        h2t[bb][hid] = h2v;
    }
    if (tid < 8) rp[tid] = -0.5f * bo2v;   // so pred(step 0) = 0
    __syncthreads();

    const float* hb1 = h1_sh + bb * 128;
    const float* hb2 = h2_sh + bb * 128;
    const float* pk  = packD1 + ((size_t)bb * 32 * H_ + hid) * 8;

    for (int s = 0; s < TGT_; s++) {
        // ===== phase 1: L0 h-dot + head partials of h2(s-1) =====
        {
            float a[4][4] = {};
#pragma unroll
            for (int k = 0; k < 32; k++) {
                const float4 h4 = *(const float4*)&hb1[k * 4];
#pragma unroll
                for (int g = 0; g < 4; g++) {
                    a[g][0] = __fmaf_rn(h4.x, w0[g][k], a[g][0]);
                    a[g][1] = __fmaf_rn(h4.y, w0[g][k], a[g][1]);
                    a[g][2] = __fmaf_rn(h4.z, w0[g][k], a[g][2]);
                    a[g][3] = __fmaf_rn(h4.w, w0[g][k], a[g][3]);
                }
            }
#pragma unroll
            for (int b = 0; b < 4; b++) {
                float4 v; v.x = a[0][b]; v.y = a[1][b]; v.z = a[2][b]; v.w = a[3][b];
                *(float4*)&zp[bb * 2048 + b * 512 + hid * 4] = v;
            }
        }
        {
            float pm[4] = {0.f, 0.f, 0.f, 0.f};
#pragma unroll
            for (int k4 = 0; k4 < 8; k4++) {
#pragma unroll
                for (int m = 0; m < 4; m++) {
                    const float4 hq = *(const float4*)&h2t[m][bb * 32 + k4 * 4]; // uniform
                    pm[m] = __fmaf_rn(hq.x, wh[k4 * 4 + 0], pm[m]);
                    pm[m] = __fmaf_rn(hq.y, wh[k4 * 4 + 1], pm[m]);
                    pm[m] = __fmaf_rn(hq.z, wh[k4 * 4 + 2], pm[m]);
                    pm[m] = __fmaf_rn(hq.w, wh[k4 * 4 + 3], pm[m]);
                }
            }
#pragma unroll
            for (int m = 0; m < 4; m++) part[bb * 512 + m * 128 + hid] = pm[m];
        }
        __syncthreads();

        // ===== phase 1b: assemble head, wave-reduce -> rp =====
        {
            float hacc = bo1j;
#pragma unroll
            for (int q = 0; q < 4; q++) hacc += part[q * 512 + bb * 128 + hid];
            float p = fmaxf(hacc, 0.f) * wo2v;
            p += __shfl_down(p, 32); p += __shfl_down(p, 16); p += __shfl_down(p, 8);
            p += __shfl_down(p, 4);  p += __shfl_down(p, 2);  p += __shfl_down(p, 1);
            if ((tid & 63) == 0) rp[tid >> 6] = p;   // wave w covers bb = w>>1
        }
        __syncthreads();

        // ===== phase 2: L0 act (+ x-term via pred), out write =====
        {
            const float pred = rp[2 * bb] + rp[2 * bb + 1] + bo2v;
            if (hid == 0 && s > 0) out[(B0 + bb) * TGT_ + (s - 1)] = pred;
            float zi = __fmaf_rn(wxi, pred, b0i);
            float zf = __fmaf_rn(wxf, pred, b0f);
            float zg = __fmaf_rn(wxg, pred, b0g);
            float zo = __fmaf_rn(wxo, pred, b0o);
#pragma unroll
            for (int q = 0; q < 4; q++) {
                const float4 v = *(const float4*)&zp[q * 2048 + bb * 512 + hid * 4];
                zi += v.x; zf += v.y; zg += v.z; zo += v.w;
            }
            c1 = sigm(zf) * c1 + sigm(zi) * tanh_f(zg);
            h1_sh[hid * 4 + bb] = sigm(zo) * tanh_f(c1);
        }
        __syncthreads();

        // ===== phase 3: L1 dot (L2 stream: 32 contiguous B per thread per k) =====
        {
            float d[4][4] = {};
#pragma unroll 8
            for (int k = 0; k < 32; k++) {
                const float4 wi = *(const float4*)&pk[(size_t)k * 1024];
                const float4 whh = *(const float4*)&pk[(size_t)k * 1024 + 4];
                const float4 p1 = *(const float4*)&hb1[k * 4];
                const float4 p2 = *(const float4*)&hb2[k * 4];
                d[0][0] = __fmaf_rn(p1.x, wi.x, __fmaf_rn(p2.x, whh.x, d[0][0]));
                d[0][1] = __fmaf_rn(p1.y, wi.x, __fmaf_rn(p2.y, whh.x, d[0][1]));
                d[0][2] = __fmaf_rn(p1.z, wi.x, __fmaf_rn(p2.z, whh.x, d[0][2]));
                d[0][3] = __fmaf_rn(p1.w, wi.x, __fmaf_rn(p2.w, whh.x, d[0][3]));
                d[1][0] = __fmaf_rn(p1.x, wi.y, __fmaf_rn(p2.x, whh.y, d[1][0]));
                d[1][1] = __fmaf_rn(p1.y, wi.y, __fmaf_rn(p2.y, whh.y, d[1][1]));
                d[1][2] = __fmaf_rn(p1.z, wi.y, __fmaf_rn(p2.z, whh.y, d[1][2]));
                d[1][3] = __fmaf_rn(p1.w, wi.y, __fmaf_rn(p2.w, whh.y, d[1][3]));
                d[2][0] = __fmaf_rn(p1.x, wi.z, __fmaf_rn(p2.x, whh.z, d[2][0]));
                d[2][1] = __fmaf_rn(p1.y, wi.z, __fmaf_rn(p2.y, whh.z, d[2][1]));
                d[2][2] = __fmaf_rn(p1.z, wi.z, __fmaf_rn(p2.z, whh.z, d[2][2]));
                d[2][3] = __fmaf_rn(p1.w, wi.z, __fmaf_rn(p2.w, whh.z, d[2][3]));
                d[3][0] = __fmaf_rn(p1.x, wi.w, __fmaf_rn(p2.x, whh.w, d[3][0]));
                d[3][1] = __fmaf_rn(p1.y, wi.w, __fmaf_rn(p2.y, whh.w, d[3][1]));
                d[3][2] = __fmaf_rn(p1.z, wi.w, __fmaf_rn(p2.z, whh.w, d[3][2]));
                d[3][3] = __fmaf_rn(p1.w, wi.w, __fmaf_rn(p2.w, whh.w, d[3][3]));
            }
#pragma unroll
            for (int b = 0; b < 4; b++) {
                float4 v; v.x = d[0][b]; v.y = d[1][b]; v.z = d[2][b]; v.w = d[3][b];
                *(float4*)&zp[bb * 2048 + b * 512 + hid * 4] = v;
            }
        }
        __syncthreads();

        // ===== phase 4: L1 act =====
        {
            float zi = b1i, zf = b1f, zg = b1g, zo = b1o;
#pragma unroll
            for (int q = 0; q < 4; q++) {
                const float4 v = *(const float4*)&zp[q * 2048 + bb * 512 + hid * 4];
                zi += v.x; zf += v.y; zg += v.z; zo += v.w;
            }
            c2 = sigm(zf) * c2 + sigm(zi) * tanh_f(zg);
            const float h2v = sigm(zo) * tanh_f(c2);
            h2_sh[hid * 4 + bb] = h2v;
            h2t[bb][hid] = h2v;
        }
        __syncthreads();
    }

    // ===== epilogue: head of final h2 -> out[..][95] =====
    {
        float pm[4] = {0.f, 0.f, 0.f, 0.f};
#pragma unroll
        for (int k4 = 0; k4 < 8; k4++) {
#pragma unroll
            for (int m = 0; m < 4; m++) {
                const float4 hq = *(const float4*)&h2t[m][bb * 32 + k4 * 4];
                pm[m] = __fmaf_rn(hq.x, wh[k4 * 4 + 0], pm[m]);
                pm[m] = __fmaf_rn(hq.y, wh[k4 * 4 + 1], pm[m]);
                pm[m] = __fmaf_rn(hq.z, wh[k4 * 4 + 2], pm[m]);
                pm[m] = __fmaf_rn(hq.w, wh[k4 * 4 + 3], pm[m]);
            }
        }
#pragma unroll
        for (int m = 0; m < 4; m++) part[bb * 512 + m * 128 + hid] = pm[m];
    }
    __syncthreads();
    {
        float hacc = bo1j;
#pragma unroll
        for (int q = 0; q < 4; q++) hacc += part[q * 512 + bb * 128 + hid];
        float p = fmaxf(hacc, 0.f) * wo2v;
        p += __shfl_down(p, 32); p += __shfl_down(p, 16); p += __shfl_down(p, 8);
        p += __shfl_down(p, 4);  p += __shfl_down(p, 2);  p += __shfl_down(p, 1);
        if ((tid & 63) == 0) rp[tid >> 6] = p;
    }
    __syncthreads();
    if (tid < 4)
        out[(B0 + tid) * TGT_ + (TGT_ - 1)] = rp[2 * tid] + rp[2 * tid + 1] + bo2v;
}

// ---------------------------------------------------------------- launch ----
extern "C" void kernel_launch(void* const* d_in, const int* in_sizes, int n_in,
                              void* d_out, int out_size, void* d_ws, size_t ws_size,
                              hipStream_t stream) {
    const float* feat  = (const float*)d_in[0];
    const float* eWih0 = (const float*)d_in[1];
    const float* eWhh0 = (const float*)d_in[2];
    const float* eB0   = (const float*)d_in[3];
    const float* eWih1 = (const float*)d_in[4];
    const float* eWhh1 = (const float*)d_in[5];
    const float* eB1   = (const float*)d_in[6];
    const float* dWih0 = (const float*)d_in[7];
    const float* dWhh0 = (const float*)d_in[8];
    const float* dB0   = (const float*)d_in[9];
    const float* dWih1 = (const float*)d_in[10];
    const float* dWhh1 = (const float*)d_in[11];
    const float* dB1   = (const float*)d_in[12];
    const float* Wo1   = (const float*)d_in[13];
    const float* bo1   = (const float*)d_in[14];
    const float* Wo2   = (const float*)d_in[15];
    const float* bo2   = (const float*)d_in[16];

    const size_t SZ_BH = (size_t)B_ * H_;     // 131072
    const size_t SZ_W  = (size_t)G_ * H_;     // 65536
    const size_t fixed_f = 4 * SZ_BH + 4 * SZ_W + 2 * SZ_W + 64;

    // CL <= 42 so X1 + ys0T stay L3-resident
    static const int cands[] = {42, 32, 28, 24, 21, 16, 14, 12, 8, 7, 6, 4, 3, 2, 1};
    int CL = 1;
    for (int ci = 0; ci < 15; ci++) {
        const size_t need = (fixed_f + (size_t)cands[ci] * B_ * (H_ + G_)) * 4;
        if (need <= ws_size) { CL = cands[ci]; break; }
    }
    const int NC = T_ / CL;

    float* ws    = (float*)d_ws;
    float* ys0T  = ws;                                   // [CL][128][1024]
    float* X1    = ys0T + (size_t)CL * B_ * H_;          // [CL][1024][512]
    float* h1S   = X1 + (size_t)CL * B_ * G_;
    float* c1S   = h1S + SZ_BH;
    float* h2S   = c1S + SZ_BH;
    float* c2S   = h2S + SZ_BH;
    float* wtE0  = c2S + SZ_BH;
    float* wtE1x = wtE0 + SZ_W;
    float* wtE1h = wtE1x + SZ_W;
    float* wtD0  = wtE1h + SZ_W;
    float* wtD1p = wtD0 + SZ_W;            // [128][128][8] = 2*SZ_W

    PrepArgs pa;
    pa.t_src[0] = eWhh0; pa.t_dst[0] = wtE0;
    pa.t_src[1] = eWih1; pa.t_dst[1] = wtE1x;
    pa.t_src[2] = eWhh1; pa.t_dst[2] = wtE1h;
    pa.t_src[3] = dWhh0; pa.t_dst[3] = wtD0;
    pa.d1x = dWih1; pa.d1h = dWhh1; pa.pack = wtD1p;
    kPrep<<<5, 256, 0, stream>>>(pa);

    for (int c = 0; c < NC; c++) {
        const int t0 = c * CL;
        kA<<<NBLK_, 512, 0, stream>>>(feat, wtE0, eWih0, eB0, ys0T, h1S, c1S, t0, CL);
        kX<<<dim3(8, 4, CL), 256, 0, stream>>>(ys0T, wtE1x, eB1, X1);
        kB2<<<NBLK_, 512, 0, stream>>>(X1, wtE1h, h2S, c2S, t0, CL);
    }
    kD<<<NBLK_, 512, 0, stream>>>(h1S, c1S, h2S, c2S,
                                  wtD0, dWih0, dB0,
                                  wtD1p, dB1,
                                  Wo1, bo1, Wo2, bo2,
                                  (float*)d_out);
}